// Round 3
// baseline (30.006 us; speedup 1.0000x reference)
//
#include <hip/hip_runtime.h>
#include <math.h>

#define TPB 512
#define WAVES 8
#define RAYS_PB 512          // rays per block tile
#define RPT 8                // RAYS_PB / 64
#define MAXK 1024            // points staged in LDS per chunk (16 KB as float4)

// ---------------------------------------------------------------------------
// Main kernel: grid = (ceil(M/512), 2, B), block = 512 (8 waves).
// Block (tile,h,b) covers rays [tile*512, tile*512+512) vs point half h.
// Points staged in LDS as (qx,qy,qz,-0.5|q|^2); wave w scans its 1/8 of the
// chunk for ALL 512 rays (8 rays/thread in regs); cross-wave max in LDS.
// Writes per-ray partial max s (s = p.q - 0.5|q|^2), per-ray pn (h==0), and
// per-(b,h) maxdist. All writes deterministic (no atomics, unique slots or
// identical-value races).
// ---------------------------------------------------------------------------
__global__ __launch_bounds__(TPB) void chamfer_main(
    const float* __restrict__ c, const float* __restrict__ depth,
    const float* __restrict__ pc,
    float* __restrict__ partmax,   // [B*2][M]
    float* __restrict__ pnbuf,     // [B][M]
    float* __restrict__ gmaxd,     // [B*2]
    int res, int M, int N, int K)
{
    __shared__ float4 spts[MAXK];                 // 16 KB
    __shared__ float red[WAVES][RAYS_PB];         // 16 KB (also reused as raw staging)
    __shared__ float smax[WAVES];

    int tile = blockIdx.x;
    int h = blockIdx.y;
    int b = blockIdx.z;
    int tid = threadIdx.x, w = tid >> 6, lane = tid & 63;

    const float* cb = c + b * 25;
    float fx = cb[16], sk = cb[17], cx = cb[18];
    float fy = cb[20], cy = cb[21];
    float ox = cb[3], oy = cb[7], oz = cb[11];

    // ---- ray setup: 8 rays per thread, ray rr = lane + 64*r within tile ----
    float px[RPT], py[RPT], pz[RPT], pn[RPT], mxs[RPT];
    #pragma unroll
    for (int r = 0; r < RPT; ++r) {
        int m = tile * RAYS_PB + lane + 64 * r;
        int mm = min(m, M - 1);
        int i = mm / res, j = mm - i * res;
        float x = (j + 0.5f) / (float)res;
        float y = (i + 0.5f) / (float)res;
        float xl = (x - cx + cy * sk / fy - sk * y / fy) / fx;
        float yl = (y - cy) / fy;
        float wx = cb[0] * xl + cb[1] * yl + cb[2] + cb[3];
        float wy = cb[4] * xl + cb[5] * yl + cb[6] + cb[7];
        float wz = cb[8] * xl + cb[9] * yl + cb[10] + cb[11];
        float dx = wx - ox, dy = wy - oy, dz = wz - oz;
        float nrm = fmaxf(sqrtf(dx * dx + dy * dy + dz * dz), 1e-12f);
        dx /= nrm; dy /= nrm; dz /= nrm;
        float d = depth[(size_t)b * M + mm];
        px[r] = fmaf(d, dx, ox);
        py[r] = fmaf(d, dy, oy);
        pz[r] = fmaf(d, dz, oz);
        pn[r] = px[r] * px[r] + py[r] * py[r] + pz[r] * pz[r];
        mxs[r] = -3.4e38f;
    }

    // ---- loop over this half's points in LDS chunks ----
    int ks = h * K;
    int khalf = max(0, min(N - ks, K));
    float mdl = -3.4e38f;
    float* raw = (float*)red;

    for (int c0 = 0; c0 < khalf; c0 += MAXK) {
        int kc = min(khalf - c0, MAXK);
        __syncthreads();   // prior spts/raw reads complete
        const float* src = pc + ((size_t)b * N + ks + c0) * 3;
        int nf = kc * 3;
        for (int i2 = tid; i2 < nf; i2 += TPB) raw[i2] = src[i2];
        __syncthreads();
        for (int p = tid; p < kc; p += TPB) {
            float qx = raw[3 * p], qy = raw[3 * p + 1], qz = raw[3 * p + 2];
            float qn = qx * qx + qy * qy + qz * qz;
            spts[p] = make_float4(qx, qy, qz, -0.5f * qn);
            float dx = qx - ox, dy = qy - oy, dz = qz - oz;
            mdl = fmaxf(mdl, dx * dx + dy * dy + dz * dz);
        }
        __syncthreads();   // spts ready

        int cpw = (kc + WAVES - 1) / WAVES;
        int s0 = min(w * cpw, kc);
        int s1 = min(s0 + cpw, kc);
        #pragma unroll 2
        for (int k = s0; k < s1; ++k) {
            float4 q = spts[k];   // wave-uniform broadcast read
            #pragma unroll
            for (int r = 0; r < RPT; ++r) {
                float s = fmaf(pz[r], q.z, q.w);
                s = fmaf(py[r], q.y, s);
                s = fmaf(px[r], q.x, s);
                mxs[r] = fmaxf(mxs[r], s);
            }
        }
    }

    // ---- maxdist partial (per wave) ----
    for (int off = 32; off; off >>= 1) mdl = fmaxf(mdl, __shfl_down(mdl, off));
    if (lane == 0) smax[w] = mdl;

    __syncthreads();   // all spts/raw reads done; safe to overwrite red
    #pragma unroll
    for (int r = 0; r < RPT; ++r) red[w][lane + 64 * r] = mxs[r];
    __syncthreads();

    // ---- combine across waves; thread tid owns ray tid (= lane + 64*w) ----
    {
        float mx = red[0][tid];
        #pragma unroll
        for (int ww = 1; ww < WAVES; ++ww) mx = fmaxf(mx, red[ww][tid]);
        // pn for ray tid lives in this thread's pn[w] (w = tid>>6): static select
        float pnk = pn[0];
        #pragma unroll
        for (int r = 1; r < RPT; ++r) if (w == r) pnk = pn[r];
        int m = tile * RAYS_PB + tid;
        if (m < M) {
            partmax[((size_t)(b * 2 + h)) * M + m] = mx;
            if (h == 0) pnbuf[(size_t)b * M + m] = pnk;
        }
    }
    if (tid == 0) {
        float m2 = smax[0];
        #pragma unroll
        for (int ww = 1; ww < WAVES; ++ww) m2 = fmaxf(m2, smax[ww]);
        gmaxd[b * 2 + h] = sqrtf(fmaxf(m2, 0.0f));  // same value from all tiles
    }
}

// ---------------------------------------------------------------------------
// Finalize: grid = B, block = 1024 (16 waves). Deterministic masked mean.
// ---------------------------------------------------------------------------
__global__ __launch_bounds__(1024) void chamfer_finalize(
    const float* __restrict__ partmax, const float* __restrict__ pnbuf,
    const float* __restrict__ gmaxd, const float* __restrict__ depth,
    float* __restrict__ out, int M)
{
    int b = blockIdx.x;
    float thr = fmaxf(gmaxd[2 * b], gmaxd[2 * b + 1]);
    float s = 0.f, cnt = 0.f;
    for (int m = threadIdx.x; m < M; m += 1024) {
        float mx = fmaxf(partmax[(size_t)(2 * b) * M + m],
                         partmax[(size_t)(2 * b + 1) * M + m]);
        float md = fmaxf(fmaf(-2.0f, mx, pnbuf[(size_t)b * M + m]), 0.0f);
        if (depth[(size_t)b * M + m] < thr) { s += md; cnt += 1.0f; }
    }
    for (int off = 32; off; off >>= 1) {
        s += __shfl_down(s, off);
        cnt += __shfl_down(cnt, off);
    }
    __shared__ float ss[16], sc[16];
    int w = threadIdx.x >> 6;
    if ((threadIdx.x & 63) == 0) { ss[w] = s; sc[w] = cnt; }
    __syncthreads();
    if (threadIdx.x == 0) {
        float S = 0.f, C = 0.f;
        #pragma unroll
        for (int ww = 0; ww < 16; ++ww) { S += ss[ww]; C += sc[ww]; }
        out[b] = S / fmaxf(C, 1.0f);
    }
}

extern "C" void kernel_launch(void* const* d_in, const int* in_sizes, int n_in,
                              void* d_out, int out_size, void* d_ws, size_t ws_size,
                              hipStream_t stream) {
    const float* c     = (const float*)d_in[0];
    const float* depth = (const float*)d_in[1];
    const float* pc    = (const float*)d_in[2];

    int B = in_sizes[0] / 25;
    int M = in_sizes[1] / B;
    int N = in_sizes[2] / (3 * B);
    int res = 1;
    while (res * res < M) ++res;

    int K = (N + 1) / 2;                      // points per half

    char* base = (char*)d_ws;
    float* partmax = (float*)base;
    size_t o1 = (size_t)B * 2 * M * sizeof(float);
    float* pnbuf = (float*)(base + o1);
    size_t o2 = o1 + (size_t)B * M * sizeof(float);
    o2 = (o2 + 255) & ~(size_t)255;
    float* gmaxd = (float*)(base + o2);

    int ntiles = (M + RAYS_PB - 1) / RAYS_PB;
    dim3 grid(ntiles, 2, B);
    chamfer_main<<<grid, TPB, 0, stream>>>(c, depth, pc, partmax, pnbuf, gmaxd,
                                           res, M, N, K);
    chamfer_finalize<<<B, 1024, 0, stream>>>(partmax, pnbuf, gmaxd, depth,
                                             (float*)d_out, M);
}